// Round 8
// baseline (127.452 us; speedup 1.0000x reference)
//
#include <hip/hip_runtime.h>

#define NN    2048   // nodes per sample
#define KNN   16     // neighbors
#define BATCH 8

__device__ __forceinline__ unsigned umin_u(unsigned a, unsigned b) { return a < b ? a : b; }

// ---------------------------------------------------------------------------
// cross-lane helpers
// ---------------------------------------------------------------------------
__device__ __forceinline__ unsigned long long bcast64(unsigned long long v, int l) {
  unsigned lo = __builtin_amdgcn_readlane((unsigned)(v & 0xffffffffu), l);
  unsigned hi = __builtin_amdgcn_readlane((unsigned)(v >> 32), l);
  return ((unsigned long long)hi << 32) | lo;
}

// per-16-lane-row shift up by 1 (lane l <- lane l-1), lane 0 of each row -> 0.
__device__ __forceinline__ unsigned long long dpp_shr1_zero(unsigned long long v) {
  int lo = __builtin_amdgcn_update_dpp(0, (int)(unsigned)(v & 0xffffffffu), 0x111, 0xf, 0xf, true);
  int hi = __builtin_amdgcn_update_dpp(0, (int)(unsigned)(v >> 32),        0x111, 0xf, 0xf, true);
  return ((unsigned long long)(unsigned)hi << 32) | (unsigned)lo;
}

// ---------------------------------------------------------------------------
// Kernel 1: exact kNN (K=16), one WAVE per node, 8 waves/block, fused GCN L1.
// Single distance pass: each lane computes its 32 candidates' sortable keys
// ONCE into a statically-indexed register array (no scratch). tau (exact
// 17th-smallest of the 64 lane-minima, rank 17 absorbs self — R6-proven) is
// selected by bitwise ballot; pass 2 ballots over the CACHED keys (no LDS
// reads, no recompute, and bitwise-identical values kill the R5 drift hole,
// so no slack is needed). Unseeded rerun kept as cheap insurance.
// ---------------------------------------------------------------------------
__global__ __launch_bounds__(512) void knn_l1_kernel(const float* __restrict__ coords,
                                                     const float* __restrict__ W1,
                                                     const float* __restrict__ b1,
                                                     int* __restrict__ nbr,
                                                     float* __restrict__ x1) {
  __shared__ float4 sP[NN];  // x,y,z,|p|^2  (32 KB)

  const int b        = blockIdx.x >> 8;          // 256 blocks per sample
  const int nodeBase = (blockIdx.x & 255) << 3;  // 8 nodes per block
  const int lane     = (int)threadIdx.x & 63;
  const int wid      = (int)threadIdx.x >> 6;

  const float* cb = coords + (size_t)b * NN * 6;
  for (int p = threadIdx.x; p < NN; p += 512) {
    const float2 v01 = *reinterpret_cast<const float2*>(cb + p * 6);
    const float2 v23 = *reinterpret_cast<const float2*>(cb + p * 6 + 2);
    float4 v; v.x = v01.x; v.y = v01.y; v.z = v23.x;
    v.w = v.x * v.x + v.y * v.y + v.z * v.z;
    sP[p] = v;
  }
  __syncthreads();

  const int i = nodeBase + wid;
  const float4 pi = sP[i];

  // ---- single distance pass: cache 32 sortable keys, track lane min ----
  unsigned key[32];          // static indices only -> stays in VGPRs
  unsigned lmin = 0xFFFFFFFFu;
#pragma unroll
  for (int it = 0; it < 32; ++it) {
    const float4 pj = sP[(it << 6) + lane];
    const float d2 = (pi.w + pj.w) - 2.0f * (pi.x * pj.x + pi.y * pj.y + pi.z * pj.z);
    unsigned u   = __float_as_uint(d2);
    unsigned k32 = u ^ (unsigned)((((int)u) >> 31) | 0x80000000);  // monotonic
    key[it] = k32;
    lmin = umin_u(lmin, k32);
  }

  // exact 17th-smallest of the 64 lane-minima (self d2~0 occupies one rank)
  unsigned tau = 0u;
  for (int bit = 31; bit >= 0; --bit) {
    const unsigned t_try = tau + ((1u << bit) - 1u);
    const unsigned long long m = __ballot(lmin <= t_try);
    if (__popcll(m) < 17) tau += (1u << bit);
  }

  // ---- selection over cached keys, tau-seeded + exact fallback ----
  unsigned long long lk  = ~0ull;                                  // lane k: k-th best
  unsigned long long kth = ((unsigned long long)tau << 32) | 0xFFFFFFFFull;

  for (int attempt = 0; attempt < 2; ++attempt) {
#pragma unroll
    for (int it = 0; it < 32; ++it) {
      const int j = (it << 6) + lane;
      const unsigned long long ck = ((unsigned long long)key[it] << 32) | (unsigned)j;
      unsigned long long mask = __ballot(ck < kth && j != i);
      while (mask) {
        const int src = __ffsll((unsigned long long)mask) - 1;
        mask &= mask - 1;
        const unsigned long long c = bcast64(ck, src);   // wave-uniform
        if (c < kth) {                                   // uniform branch
          const unsigned long long pk = dpp_shr1_zero(lk);
          lk = (lk < c) ? lk : (pk < c ? c : pk);        // sorted shift-insert
          const unsigned long long nk = bcast64(lk, 15);
          kth = (nk < kth) ? nk : kth;                   // monotone tighten
        }
      }
    }
    if (bcast64(lk, 15) != ~0ull) break;  // 16 real entries -> done (uniform)
    lk = ~0ull; kth = ~0ull;              // rare: rerun unseeded (exact path)
  }

  // clamped index: a sentinel can never reach memory
  const int nj = (int)umin_u((unsigned)(lk & 0xffffffffu), NN - 1u);
  if (lane < KNN) {
    nbr[((size_t)b * NN + i) * KNN + lane] = nj;
  }

  // ---- fused GCN layer 1: x1[i] = relu( ((sum_nbr c + c_i)/17) @ W1 + b1 ) ----
  float r[6];
#pragma unroll
  for (int c = 0; c < 6; ++c) r[c] = 0.f;
  if (lane < KNN) {
    const float* row = cb + (size_t)nj * 6;
    const float2 a = *reinterpret_cast<const float2*>(row);
    const float2 m = *reinterpret_cast<const float2*>(row + 2);
    const float2 q = *reinterpret_cast<const float2*>(row + 4);
    r[0] = a.x; r[1] = a.y; r[2] = m.x; r[3] = m.y; r[4] = q.x; r[5] = q.y;
  }
#pragma unroll
  for (int m = 1; m <= 8; m <<= 1) {
#pragma unroll
    for (int c = 0; c < 6; ++c) r[c] += __shfl_xor(r[c], m);
  }
  const float* self = cb + (size_t)i * 6;
  float agg[6];
#pragma unroll
  for (int c = 0; c < 6; ++c) {
    const float nbs = __uint_as_float(__builtin_amdgcn_readfirstlane(__float_as_uint(r[c])));
    agg[c] = (nbs + self[c]) * (1.0f / 17.0f);
  }
  float acc = b1[lane];
#pragma unroll
  for (int c = 0; c < 6; ++c) acc = fmaf(agg[c], W1[c * 64 + lane], acc);
  x1[((size_t)b * NN + i) * 64 + lane] = fmaxf(acc, 0.f);
}

// ---------------------------------------------------------------------------
// Kernel 2: fused GCN layer 2 + final Linear, register-tiled.
//   sA = (sum_nbr x1 + x1)/17 ; sB = relu(sA @ W2 + b2) ; out = sB @ Wf + bf
// 64 nodes / 256 threads / block (256 blocks, 55 KB LDS -> LDS caps at 2/CU,
// grid gives 1/CU). Phases B/C: thread = 8 nodes x 4 outputs -> each W float4
// feeds 32 FMAs (2x less L1 W traffic than R7's 4-node tile); sA/sB read as
// float2 pairs (halves LDS-pipe instruction count under the VALU roof).
// ---------------------------------------------------------------------------
__global__ __launch_bounds__(256) void layers_kernel(const float* __restrict__ x1,
                                                     const int* __restrict__ nbr,
                                                     const float* __restrict__ W2,
                                                     const float* __restrict__ b2,
                                                     const float* __restrict__ Wf,
                                                     const float* __restrict__ bf,
                                                     float* __restrict__ out) {
  __shared__ float sA[64][68];    // aggregated x1 (pad 4)        17.4 KB
  __shared__ float sB[64][132];   // x2 tile      (pad 4)         33.8 KB
  __shared__ int   sN[1024];      // 64 nodes x 16 nbrs            4 KB

  const int t        = (int)threadIdx.x;
  const int nodeBase = blockIdx.x * 64;
  const int bs       = nodeBase >> 11;          // sample index (64 | 2048)

  // neighbor lists for 64 nodes (clamped: sentinel can never reach memory)
#pragma unroll
  for (int q = 0; q < 4; ++q)
    sN[t + q * 256] = (int)umin_u((unsigned)nbr[(size_t)nodeBase * KNN + t + q * 256], NN - 1u);
  __syncthreads();

  // Phase A: gather-aggregate x1 (thread = node t>>2, dims (t&3)*16 .. +15)
  {
    const int ln = t >> 2;
    const int d0 = (t & 3) * 16;
    const int n  = nodeBase + ln;
    const float* Xb = x1 + (((size_t)bs) << 11) * 64;
    const float* xn = x1 + (size_t)n * 64 + d0;
    float4 s0 = *reinterpret_cast<const float4*>(xn);
    float4 s1 = *reinterpret_cast<const float4*>(xn + 4);
    float4 s2 = *reinterpret_cast<const float4*>(xn + 8);
    float4 s3 = *reinterpret_cast<const float4*>(xn + 12);
    const int* nb = &sN[ln * 16];
#pragma unroll
    for (int k = 0; k < KNN; ++k) {
      const float* row = Xb + (size_t)nb[k] * 64 + d0;
      const float4 v0 = *reinterpret_cast<const float4*>(row);
      const float4 v1 = *reinterpret_cast<const float4*>(row + 4);
      const float4 v2 = *reinterpret_cast<const float4*>(row + 8);
      const float4 v3 = *reinterpret_cast<const float4*>(row + 12);
      s0.x += v0.x; s0.y += v0.y; s0.z += v0.z; s0.w += v0.w;
      s1.x += v1.x; s1.y += v1.y; s1.z += v1.z; s1.w += v1.w;
      s2.x += v2.x; s2.y += v2.y; s2.z += v2.z; s2.w += v2.w;
      s3.x += v3.x; s3.y += v3.y; s3.z += v3.z; s3.w += v3.w;
    }
    const float sc = 1.0f / 17.0f;
    float* dst = &sA[ln][d0];
    dst[0]  = s0.x * sc; dst[1]  = s0.y * sc; dst[2]  = s0.z * sc; dst[3]  = s0.w * sc;
    dst[4]  = s1.x * sc; dst[5]  = s1.y * sc; dst[6]  = s1.z * sc; dst[7]  = s1.w * sc;
    dst[8]  = s2.x * sc; dst[9]  = s2.y * sc; dst[10] = s2.z * sc; dst[11] = s2.w * sc;
    dst[12] = s3.x * sc; dst[13] = s3.y * sc; dst[14] = s3.z * sc; dst[15] = s3.w * sc;
  }
  __syncthreads();

  const int ng = (t >> 5) * 8;   // first of 8 nodes
  const int o4 = (t & 31) * 4;   // 4 outputs

  // Phase B: x2 = relu(sA @ W2 + b2) -> sB  (K=64, c in float2 pairs)
  {
    const float4 bv = *reinterpret_cast<const float4*>(b2 + o4);
    float4 a0 = bv, a1 = bv, a2 = bv, a3 = bv, a4 = bv, a5 = bv, a6 = bv, a7 = bv;
#pragma unroll 4
    for (int c = 0; c < 64; c += 2) {
      const float4 wA = *reinterpret_cast<const float4*>(W2 + (size_t)c * 128 + o4);
      const float4 wB = *reinterpret_cast<const float4*>(W2 + (size_t)(c + 1) * 128 + o4);
#define STEP_B(q, acc) { const float2 a = *reinterpret_cast<const float2*>(&sA[ng + q][c]); \
      acc.x += a.x * wA.x + a.y * wB.x; acc.y += a.x * wA.y + a.y * wB.y;                   \
      acc.z += a.x * wA.z + a.y * wB.z; acc.w += a.x * wA.w + a.y * wB.w; }
      STEP_B(0, a0) STEP_B(1, a1) STEP_B(2, a2) STEP_B(3, a3)
      STEP_B(4, a4) STEP_B(5, a5) STEP_B(6, a6) STEP_B(7, a7)
#undef STEP_B
    }
#define STORE_B(q, acc) { float* d = &sB[ng + q][o4];                        \
    d[0] = fmaxf(acc.x, 0.f); d[1] = fmaxf(acc.y, 0.f);                      \
    d[2] = fmaxf(acc.z, 0.f); d[3] = fmaxf(acc.w, 0.f); }
    STORE_B(0, a0) STORE_B(1, a1) STORE_B(2, a2) STORE_B(3, a3)
    STORE_B(4, a4) STORE_B(5, a5) STORE_B(6, a6) STORE_B(7, a7)
#undef STORE_B
  }
  __syncthreads();

  // Phase C: out = sB @ Wf + bf  (K=128, c in float2 pairs)
  {
    const float4 bv = *reinterpret_cast<const float4*>(bf + o4);
    float4 a0 = bv, a1 = bv, a2 = bv, a3 = bv, a4 = bv, a5 = bv, a6 = bv, a7 = bv;
#pragma unroll 4
    for (int c = 0; c < 128; c += 2) {
      const float4 wA = *reinterpret_cast<const float4*>(Wf + (size_t)c * 128 + o4);
      const float4 wB = *reinterpret_cast<const float4*>(Wf + (size_t)(c + 1) * 128 + o4);
#define STEP_C(q, acc) { const float2 a = *reinterpret_cast<const float2*>(&sB[ng + q][c]); \
      acc.x += a.x * wA.x + a.y * wB.x; acc.y += a.x * wA.y + a.y * wB.y;                   \
      acc.z += a.x * wA.z + a.y * wB.z; acc.w += a.x * wA.w + a.y * wB.w; }
      STEP_C(0, a0) STEP_C(1, a1) STEP_C(2, a2) STEP_C(3, a3)
      STEP_C(4, a4) STEP_C(5, a5) STEP_C(6, a6) STEP_C(7, a7)
#undef STEP_C
    }
    float* o0 = out + (size_t)(nodeBase + ng) * 128 + o4;
    *reinterpret_cast<float4*>(o0)       = a0;
    *reinterpret_cast<float4*>(o0 + 128) = a1;
    *reinterpret_cast<float4*>(o0 + 256) = a2;
    *reinterpret_cast<float4*>(o0 + 384) = a3;
    *reinterpret_cast<float4*>(o0 + 512) = a4;
    *reinterpret_cast<float4*>(o0 + 640) = a5;
    *reinterpret_cast<float4*>(o0 + 768) = a6;
    *reinterpret_cast<float4*>(o0 + 896) = a7;
  }
}

// ---------------------------------------------------------------------------
extern "C" void kernel_launch(void* const* d_in, const int* in_sizes, int n_in,
                              void* d_out, int out_size, void* d_ws, size_t ws_size,
                              hipStream_t stream) {
  const float* coords = (const float*)d_in[0];
  const float* W1 = (const float*)d_in[1];
  const float* b1 = (const float*)d_in[2];
  const float* W2 = (const float*)d_in[3];
  const float* b2 = (const float*)d_in[4];
  const float* Wf = (const float*)d_in[5];
  const float* bf = (const float*)d_in[6];
  float* out = (float*)d_out;

  char* ws = (char*)d_ws;
  int*   nbr = (int*)ws;                              // 1 MB
  float* x1  = (float*)(ws + (size_t)(1u << 20) * 1); // 4 MB

  // kNN + layer 1: one wave per node, 8 waves/block
  knn_l1_kernel<<<BATCH * (NN / 8), 512, 0, stream>>>(coords, W1, b1, nbr, x1);

  // layer 2 (aggregate + 64->128 + relu) fused with final 128->128 linear
  layers_kernel<<<(BATCH * NN) / 64, 256, 0, stream>>>(x1, nbr, W2, b2, Wf, bf, out);
}

// Round 9
// 121.241 us; speedup vs baseline: 1.0512x; 1.0512x over previous
//
#include <hip/hip_runtime.h>

#define NN    2048   // nodes per sample
#define KNN   16     // neighbors
#define BATCH 8

__device__ __forceinline__ unsigned umin_u(unsigned a, unsigned b) { return a < b ? a : b; }

// ---------------------------------------------------------------------------
// cross-lane helpers
// ---------------------------------------------------------------------------
__device__ __forceinline__ unsigned long long bcast64(unsigned long long v, int l) {
  unsigned lo = __builtin_amdgcn_readlane((unsigned)(v & 0xffffffffu), l);
  unsigned hi = __builtin_amdgcn_readlane((unsigned)(v >> 32), l);
  return ((unsigned long long)hi << 32) | lo;
}

// per-16-lane-row shift up by 1 (lane l <- lane l-1), lane 0 of each row -> 0.
__device__ __forceinline__ unsigned long long dpp_shr1_zero(unsigned long long v) {
  int lo = __builtin_amdgcn_update_dpp(0, (int)(unsigned)(v & 0xffffffffu), 0x111, 0xf, 0xf, true);
  int hi = __builtin_amdgcn_update_dpp(0, (int)(unsigned)(v >> 32),        0x111, 0xf, 0xf, true);
  return ((unsigned long long)(unsigned)hi << 32) | (unsigned)lo;
}

// ---------------------------------------------------------------------------
// Kernel 1: exact kNN (K=16), one WAVE per node, 8 waves/block, fused GCN L1.
// (unchanged from R8 — single distance pass with register-cached keys; tau =
// exact 17th-smallest of lane-minima; cached keys make pass-1/pass-2 values
// bitwise identical, closing the R5 contraction-drift hole; unseeded rerun
// kept as insurance; all gathered indices clamped.)
// ---------------------------------------------------------------------------
__global__ __launch_bounds__(512) void knn_l1_kernel(const float* __restrict__ coords,
                                                     const float* __restrict__ W1,
                                                     const float* __restrict__ b1,
                                                     int* __restrict__ nbr,
                                                     float* __restrict__ x1) {
  __shared__ float4 sP[NN];  // x,y,z,|p|^2  (32 KB)

  const int b        = blockIdx.x >> 8;          // 256 blocks per sample
  const int nodeBase = (blockIdx.x & 255) << 3;  // 8 nodes per block
  const int lane     = (int)threadIdx.x & 63;
  const int wid      = (int)threadIdx.x >> 6;

  const float* cb = coords + (size_t)b * NN * 6;
  for (int p = threadIdx.x; p < NN; p += 512) {
    const float2 v01 = *reinterpret_cast<const float2*>(cb + p * 6);
    const float2 v23 = *reinterpret_cast<const float2*>(cb + p * 6 + 2);
    float4 v; v.x = v01.x; v.y = v01.y; v.z = v23.x;
    v.w = v.x * v.x + v.y * v.y + v.z * v.z;
    sP[p] = v;
  }
  __syncthreads();

  const int i = nodeBase + wid;
  const float4 pi = sP[i];

  // ---- single distance pass: cache 32 sortable keys, track lane min ----
  unsigned key[32];          // static indices only -> stays in VGPRs
  unsigned lmin = 0xFFFFFFFFu;
#pragma unroll
  for (int it = 0; it < 32; ++it) {
    const float4 pj = sP[(it << 6) + lane];
    const float d2 = (pi.w + pj.w) - 2.0f * (pi.x * pj.x + pi.y * pj.y + pi.z * pj.z);
    unsigned u   = __float_as_uint(d2);
    unsigned k32 = u ^ (unsigned)((((int)u) >> 31) | 0x80000000);  // monotonic
    key[it] = k32;
    lmin = umin_u(lmin, k32);
  }

  // exact 17th-smallest of the 64 lane-minima (self d2~0 occupies one rank)
  unsigned tau = 0u;
  for (int bit = 31; bit >= 0; --bit) {
    const unsigned t_try = tau + ((1u << bit) - 1u);
    const unsigned long long m = __ballot(lmin <= t_try);
    if (__popcll(m) < 17) tau += (1u << bit);
  }

  // ---- selection over cached keys, tau-seeded + exact fallback ----
  unsigned long long lk  = ~0ull;                                  // lane k: k-th best
  unsigned long long kth = ((unsigned long long)tau << 32) | 0xFFFFFFFFull;

  for (int attempt = 0; attempt < 2; ++attempt) {
#pragma unroll
    for (int it = 0; it < 32; ++it) {
      const int j = (it << 6) + lane;
      const unsigned long long ck = ((unsigned long long)key[it] << 32) | (unsigned)j;
      unsigned long long mask = __ballot(ck < kth && j != i);
      while (mask) {
        const int src = __ffsll((unsigned long long)mask) - 1;
        mask &= mask - 1;
        const unsigned long long c = bcast64(ck, src);   // wave-uniform
        if (c < kth) {                                   // uniform branch
          const unsigned long long pk = dpp_shr1_zero(lk);
          lk = (lk < c) ? lk : (pk < c ? c : pk);        // sorted shift-insert
          const unsigned long long nk = bcast64(lk, 15);
          kth = (nk < kth) ? nk : kth;                   // monotone tighten
        }
      }
    }
    if (bcast64(lk, 15) != ~0ull) break;  // 16 real entries -> done (uniform)
    lk = ~0ull; kth = ~0ull;              // rare: rerun unseeded (exact path)
  }

  // clamped index: a sentinel can never reach memory
  const int nj = (int)umin_u((unsigned)(lk & 0xffffffffu), NN - 1u);
  if (lane < KNN) {
    nbr[((size_t)b * NN + i) * KNN + lane] = nj;
  }

  // ---- fused GCN layer 1: x1[i] = relu( ((sum_nbr c + c_i)/17) @ W1 + b1 ) ----
  float r[6];
#pragma unroll
  for (int c = 0; c < 6; ++c) r[c] = 0.f;
  if (lane < KNN) {
    const float* row = cb + (size_t)nj * 6;
    const float2 a = *reinterpret_cast<const float2*>(row);
    const float2 m = *reinterpret_cast<const float2*>(row + 2);
    const float2 q = *reinterpret_cast<const float2*>(row + 4);
    r[0] = a.x; r[1] = a.y; r[2] = m.x; r[3] = m.y; r[4] = q.x; r[5] = q.y;
  }
#pragma unroll
  for (int m = 1; m <= 8; m <<= 1) {
#pragma unroll
    for (int c = 0; c < 6; ++c) r[c] += __shfl_xor(r[c], m);
  }
  const float* self = cb + (size_t)i * 6;
  float agg[6];
#pragma unroll
  for (int c = 0; c < 6; ++c) {
    const float nbs = __uint_as_float(__builtin_amdgcn_readfirstlane(__float_as_uint(r[c])));
    agg[c] = (nbs + self[c]) * (1.0f / 17.0f);
  }
  float acc = b1[lane];
#pragma unroll
  for (int c = 0; c < 6; ++c) acc = fmaf(agg[c], W1[c * 64 + lane], acc);
  x1[((size_t)b * NN + i) * 64 + lane] = fmaxf(acc, 0.f);
}

// ---------------------------------------------------------------------------
// Kernel 2: fused GCN layer 2 + final Linear, register-tiled (R7-proven shape).
//   sA = (sum_nbr x1 + x1)/17 ; sB = relu(sA @ W2 + b2) ; out = sB @ Wf + bf
// 32 nodes / 256 threads / block, 512 blocks (2 blocks/CU). Thread = 4 nodes
// x 4 outputs -> each W float4 feeds 16 FMAs. NEW: XCD-aware bijective
// swizzle (512 = 8 XCD x 64) puts all 64 blocks of one sample on one XCD so
// the Phase-A x1 gather (512 KB/sample) stays L2-local.
// ---------------------------------------------------------------------------
__global__ __launch_bounds__(256) void layers_kernel(const float* __restrict__ x1,
                                                     const int* __restrict__ nbr,
                                                     const float* __restrict__ W2,
                                                     const float* __restrict__ b2,
                                                     const float* __restrict__ Wf,
                                                     const float* __restrict__ bf,
                                                     float* __restrict__ out) {
  __shared__ float sA[32][68];    // aggregated x1 (pad 4)
  __shared__ float sB[32][132];   // x2 tile      (pad 4)
  __shared__ int   sN[512];

  const int t   = (int)threadIdx.x;
  const int bid = (int)blockIdx.x;
  // XCD swizzle: XCD k (= bid%8) exclusively processes sample k's 64 tiles
  const int swz = (bid & 7) * 64 + (bid >> 3);
  const int nodeBase = swz * 32;
  const int bs       = nodeBase >> 11;          // sample index (32 | 2048)

  // neighbor lists for 32 nodes (clamped: sentinel can never reach memory)
  sN[t]       = (int)umin_u((unsigned)nbr[(size_t)nodeBase * KNN + t],       NN - 1u);
  sN[t + 256] = (int)umin_u((unsigned)nbr[(size_t)nodeBase * KNN + t + 256], NN - 1u);
  __syncthreads();

  // Phase A: gather-aggregate x1 (thread = node t>>3, dims (t&7)*8 .. +7)
  {
    const int ln = t >> 3;
    const int d8 = (t & 7) * 8;
    const int n  = nodeBase + ln;
    const float* Xb = x1 + (((size_t)bs) << 11) * 64;
    const float* xn = x1 + (size_t)n * 64 + d8;
    float4 s0 = *reinterpret_cast<const float4*>(xn);
    float4 s1 = *reinterpret_cast<const float4*>(xn + 4);
    const int* nb = &sN[ln * 16];
#pragma unroll
    for (int k = 0; k < KNN; ++k) {
      const float* row = Xb + (size_t)nb[k] * 64 + d8;
      const float4 v0 = *reinterpret_cast<const float4*>(row);
      const float4 v1 = *reinterpret_cast<const float4*>(row + 4);
      s0.x += v0.x; s0.y += v0.y; s0.z += v0.z; s0.w += v0.w;
      s1.x += v1.x; s1.y += v1.y; s1.z += v1.z; s1.w += v1.w;
    }
    const float sc = 1.0f / 17.0f;
    sA[ln][d8 + 0] = s0.x * sc; sA[ln][d8 + 1] = s0.y * sc;
    sA[ln][d8 + 2] = s0.z * sc; sA[ln][d8 + 3] = s0.w * sc;
    sA[ln][d8 + 4] = s1.x * sc; sA[ln][d8 + 5] = s1.y * sc;
    sA[ln][d8 + 6] = s1.z * sc; sA[ln][d8 + 7] = s1.w * sc;
  }
  __syncthreads();

  const int ng = (t >> 5) * 4;   // first of 4 nodes
  const int o4 = (t & 31) * 4;   // 4 outputs

  // Phase B: x2 = relu(sA @ W2 + b2) -> sB  (K=64)
  {
    const float4 bv = *reinterpret_cast<const float4*>(b2 + o4);
    float4 acc0 = bv, acc1 = bv, acc2 = bv, acc3 = bv;
#pragma unroll 4
    for (int c = 0; c < 64; ++c) {
      const float4 w = *reinterpret_cast<const float4*>(W2 + (size_t)c * 128 + o4);
      const float a0 = sA[ng + 0][c];
      const float a1 = sA[ng + 1][c];
      const float a2 = sA[ng + 2][c];
      const float a3 = sA[ng + 3][c];
      acc0.x += a0 * w.x; acc0.y += a0 * w.y; acc0.z += a0 * w.z; acc0.w += a0 * w.w;
      acc1.x += a1 * w.x; acc1.y += a1 * w.y; acc1.z += a1 * w.z; acc1.w += a1 * w.w;
      acc2.x += a2 * w.x; acc2.y += a2 * w.y; acc2.z += a2 * w.z; acc2.w += a2 * w.w;
      acc3.x += a3 * w.x; acc3.y += a3 * w.y; acc3.z += a3 * w.z; acc3.w += a3 * w.w;
    }
    sB[ng + 0][o4 + 0] = fmaxf(acc0.x, 0.f); sB[ng + 0][o4 + 1] = fmaxf(acc0.y, 0.f);
    sB[ng + 0][o4 + 2] = fmaxf(acc0.z, 0.f); sB[ng + 0][o4 + 3] = fmaxf(acc0.w, 0.f);
    sB[ng + 1][o4 + 0] = fmaxf(acc1.x, 0.f); sB[ng + 1][o4 + 1] = fmaxf(acc1.y, 0.f);
    sB[ng + 1][o4 + 2] = fmaxf(acc1.z, 0.f); sB[ng + 1][o4 + 3] = fmaxf(acc1.w, 0.f);
    sB[ng + 2][o4 + 0] = fmaxf(acc2.x, 0.f); sB[ng + 2][o4 + 1] = fmaxf(acc2.y, 0.f);
    sB[ng + 2][o4 + 2] = fmaxf(acc2.z, 0.f); sB[ng + 2][o4 + 3] = fmaxf(acc2.w, 0.f);
    sB[ng + 3][o4 + 0] = fmaxf(acc3.x, 0.f); sB[ng + 3][o4 + 1] = fmaxf(acc3.y, 0.f);
    sB[ng + 3][o4 + 2] = fmaxf(acc3.z, 0.f); sB[ng + 3][o4 + 3] = fmaxf(acc3.w, 0.f);
  }
  __syncthreads();

  // Phase C: out = sB @ Wf + bf  (K=128)
  {
    const float4 bv = *reinterpret_cast<const float4*>(bf + o4);
    float4 acc0 = bv, acc1 = bv, acc2 = bv, acc3 = bv;
#pragma unroll 4
    for (int c = 0; c < 128; ++c) {
      const float4 w = *reinterpret_cast<const float4*>(Wf + (size_t)c * 128 + o4);
      const float a0 = sB[ng + 0][c];
      const float a1 = sB[ng + 1][c];
      const float a2 = sB[ng + 2][c];
      const float a3 = sB[ng + 3][c];
      acc0.x += a0 * w.x; acc0.y += a0 * w.y; acc0.z += a0 * w.z; acc0.w += a0 * w.w;
      acc1.x += a1 * w.x; acc1.y += a1 * w.y; acc1.z += a1 * w.z; acc1.w += a1 * w.w;
      acc2.x += a2 * w.x; acc2.y += a2 * w.y; acc2.z += a2 * w.z; acc2.w += a2 * w.w;
      acc3.x += a3 * w.x; acc3.y += a3 * w.y; acc3.z += a3 * w.z; acc3.w += a3 * w.w;
    }
    float* o0 = out + (size_t)(nodeBase + ng) * 128 + o4;
    *reinterpret_cast<float4*>(o0)       = acc0;
    *reinterpret_cast<float4*>(o0 + 128) = acc1;
    *reinterpret_cast<float4*>(o0 + 256) = acc2;
    *reinterpret_cast<float4*>(o0 + 384) = acc3;
  }
}

// ---------------------------------------------------------------------------
extern "C" void kernel_launch(void* const* d_in, const int* in_sizes, int n_in,
                              void* d_out, int out_size, void* d_ws, size_t ws_size,
                              hipStream_t stream) {
  const float* coords = (const float*)d_in[0];
  const float* W1 = (const float*)d_in[1];
  const float* b1 = (const float*)d_in[2];
  const float* W2 = (const float*)d_in[3];
  const float* b2 = (const float*)d_in[4];
  const float* Wf = (const float*)d_in[5];
  const float* bf = (const float*)d_in[6];
  float* out = (float*)d_out;

  char* ws = (char*)d_ws;
  int*   nbr = (int*)ws;                              // 1 MB
  float* x1  = (float*)(ws + (size_t)(1u << 20) * 1); // 4 MB

  // kNN + layer 1: one wave per node, 8 waves/block
  knn_l1_kernel<<<BATCH * (NN / 8), 512, 0, stream>>>(coords, W1, b1, nbr, x1);

  // layer 2 (aggregate + 64->128 + relu) fused with final 128->128 linear
  layers_kernel<<<(BATCH * NN) / 32, 256, 0, stream>>>(x1, nbr, W2, b2, Wf, bf, out);
}

// Round 10
// 113.055 us; speedup vs baseline: 1.1273x; 1.0724x over previous
//
#include <hip/hip_runtime.h>

#define NN    2048   // nodes per sample
#define KNN   16     // neighbors
#define BATCH 8

__device__ __forceinline__ unsigned umin_u(unsigned a, unsigned b) { return a < b ? a : b; }

// ---------------------------------------------------------------------------
// cross-lane helpers
// ---------------------------------------------------------------------------
__device__ __forceinline__ unsigned long long bcast64(unsigned long long v, int l) {
  unsigned lo = __builtin_amdgcn_readlane((unsigned)(v & 0xffffffffu), l);
  unsigned hi = __builtin_amdgcn_readlane((unsigned)(v >> 32), l);
  return ((unsigned long long)hi << 32) | lo;
}

// per-16-lane-row shift up by 1 (lane l <- lane l-1), lane 0 of each row -> 0.
__device__ __forceinline__ unsigned long long dpp_shr1_zero(unsigned long long v) {
  int lo = __builtin_amdgcn_update_dpp(0, (int)(unsigned)(v & 0xffffffffu), 0x111, 0xf, 0xf, true);
  int hi = __builtin_amdgcn_update_dpp(0, (int)(unsigned)(v >> 32),        0x111, 0xf, 0xf, true);
  return ((unsigned long long)(unsigned)hi << 32) | (unsigned)lo;
}

// ---------------------------------------------------------------------------
// Kernel 1: exact kNN (K=16), one WAVE per node, 8 waves/block, fused GCN L1.
// Single distance pass caches each lane's 32 sortable keys in registers.
// tau = exact 17th-smallest of the 64 lane-minima (rank 17 absorbs self);
// over the cached keys, ">=16 non-self keys <= tau" is a theorem, so the
// selection ballots against the CONSTANT tau (32-bit compare) and does a
// BRANCHLESS sorted insert of every survivor:
//   pk = row-shift(lk);  lk = min(lk, max(pk, c))
// (list lanes ascending; pk<=lk, so this is the shift-insert) — no running
// kth, no scalar compares, no inner branch. ~25 inserts/node total.
// Unseeded rerun kept as insurance; gathered indices clamped.
// ---------------------------------------------------------------------------
__global__ __launch_bounds__(512) void knn_l1_kernel(const float* __restrict__ coords,
                                                     const float* __restrict__ W1,
                                                     const float* __restrict__ b1,
                                                     int* __restrict__ nbr,
                                                     float* __restrict__ x1) {
  __shared__ float4 sP[NN];  // x,y,z,|p|^2  (32 KB)

  const int b        = blockIdx.x >> 8;          // 256 blocks per sample
  const int nodeBase = (blockIdx.x & 255) << 3;  // 8 nodes per block
  const int lane     = (int)threadIdx.x & 63;
  const int wid      = (int)threadIdx.x >> 6;

  const float* cb = coords + (size_t)b * NN * 6;
  for (int p = threadIdx.x; p < NN; p += 512) {
    const float2 v01 = *reinterpret_cast<const float2*>(cb + p * 6);
    const float2 v23 = *reinterpret_cast<const float2*>(cb + p * 6 + 2);
    float4 v; v.x = v01.x; v.y = v01.y; v.z = v23.x;
    v.w = v.x * v.x + v.y * v.y + v.z * v.z;
    sP[p] = v;
  }
  __syncthreads();

  const int i = nodeBase + wid;
  const float4 pi = sP[i];

  // ---- single distance pass: cache 32 sortable keys, track lane min ----
  unsigned key[32];          // static indices only -> stays in VGPRs
  unsigned lmin = 0xFFFFFFFFu;
#pragma unroll
  for (int it = 0; it < 32; ++it) {
    const float4 pj = sP[(it << 6) + lane];
    const float d2 = (pi.w + pj.w) - 2.0f * (pi.x * pj.x + pi.y * pj.y + pi.z * pj.z);
    unsigned u   = __float_as_uint(d2);
    unsigned k32 = u ^ (unsigned)((((int)u) >> 31) | 0x80000000);  // monotonic
    key[it] = k32;
    lmin = umin_u(lmin, k32);
  }

  // exact 17th-smallest of the 64 lane-minima (self d2~0 occupies one rank)
  unsigned tau = 0u;
  for (int bit = 31; bit >= 0; --bit) {
    const unsigned t_try = tau + ((1u << bit) - 1u);
    const unsigned long long m = __ballot(lmin <= t_try);
    if (__popcll(m) < 17) tau += (1u << bit);
  }

  // ---- selection over cached keys: constant-tau ballot, branchless insert --
  unsigned long long lk = ~0ull;   // lane k (k<16): k-th smallest so far
  unsigned thr = tau;

  for (int attempt = 0; attempt < 2; ++attempt) {
#pragma unroll
    for (int it = 0; it < 32; ++it) {
      const int j = (it << 6) + lane;
      const unsigned long long ck = ((unsigned long long)key[it] << 32) | (unsigned)j;
      unsigned long long mask = __ballot(key[it] <= thr && j != i);
      while (mask) {
        const int src = __ffsll((unsigned long long)mask) - 1;
        mask &= mask - 1;
        const unsigned long long c  = bcast64(ck, src);       // wave-uniform
        const unsigned long long pk = dpp_shr1_zero(lk);      // row shift-up
        const unsigned long long mx = (pk > c) ? pk : c;
        lk = (lk < mx) ? lk : mx;                             // sorted insert
      }
    }
    if (bcast64(lk, 15) != ~0ull) break;  // >=16 entries (always true in practice)
    lk = ~0ull; thr = 0xFFFFFFFFu;        // insurance: exact unseeded rerun
  }

  // clamped index: a sentinel can never reach memory
  const int nj = (int)umin_u((unsigned)(lk & 0xffffffffu), NN - 1u);
  if (lane < KNN) {
    nbr[((size_t)b * NN + i) * KNN + lane] = nj;
  }

  // ---- fused GCN layer 1: x1[i] = relu( ((sum_nbr c + c_i)/17) @ W1 + b1 ) ----
  float r[6];
#pragma unroll
  for (int c = 0; c < 6; ++c) r[c] = 0.f;
  if (lane < KNN) {
    const float* row = cb + (size_t)nj * 6;
    const float2 a = *reinterpret_cast<const float2*>(row);
    const float2 m = *reinterpret_cast<const float2*>(row + 2);
    const float2 q = *reinterpret_cast<const float2*>(row + 4);
    r[0] = a.x; r[1] = a.y; r[2] = m.x; r[3] = m.y; r[4] = q.x; r[5] = q.y;
  }
#pragma unroll
  for (int m = 1; m <= 8; m <<= 1) {
#pragma unroll
    for (int c = 0; c < 6; ++c) r[c] += __shfl_xor(r[c], m);
  }
  const float* self = cb + (size_t)i * 6;
  float agg[6];
#pragma unroll
  for (int c = 0; c < 6; ++c) {
    const float nbs = __uint_as_float(__builtin_amdgcn_readfirstlane(__float_as_uint(r[c])));
    agg[c] = (nbs + self[c]) * (1.0f / 17.0f);
  }
  float acc = b1[lane];
#pragma unroll
  for (int c = 0; c < 6; ++c) acc = fmaf(agg[c], W1[c * 64 + lane], acc);
  x1[((size_t)b * NN + i) * 64 + lane] = fmaxf(acc, 0.f);
}

// ---------------------------------------------------------------------------
// Kernel 2: fused GCN layer 2 + final Linear, register-tiled (R9 shape,
// unchanged: 32 nodes / 256 threads / 512 blocks, XCD-swizzled).
// ---------------------------------------------------------------------------
__global__ __launch_bounds__(256) void layers_kernel(const float* __restrict__ x1,
                                                     const int* __restrict__ nbr,
                                                     const float* __restrict__ W2,
                                                     const float* __restrict__ b2,
                                                     const float* __restrict__ Wf,
                                                     const float* __restrict__ bf,
                                                     float* __restrict__ out) {
  __shared__ float sA[32][68];    // aggregated x1 (pad 4)
  __shared__ float sB[32][132];   // x2 tile      (pad 4)
  __shared__ int   sN[512];

  const int t   = (int)threadIdx.x;
  const int bid = (int)blockIdx.x;
  // XCD swizzle: XCD k (= bid%8) exclusively processes sample k's 64 tiles
  const int swz = (bid & 7) * 64 + (bid >> 3);
  const int nodeBase = swz * 32;
  const int bs       = nodeBase >> 11;          // sample index (32 | 2048)

  // neighbor lists for 32 nodes (clamped: sentinel can never reach memory)
  sN[t]       = (int)umin_u((unsigned)nbr[(size_t)nodeBase * KNN + t],       NN - 1u);
  sN[t + 256] = (int)umin_u((unsigned)nbr[(size_t)nodeBase * KNN + t + 256], NN - 1u);
  __syncthreads();

  // Phase A: gather-aggregate x1 (thread = node t>>3, dims (t&7)*8 .. +7)
  {
    const int ln = t >> 3;
    const int d8 = (t & 7) * 8;
    const int n  = nodeBase + ln;
    const float* Xb = x1 + (((size_t)bs) << 11) * 64;
    const float* xn = x1 + (size_t)n * 64 + d8;
    float4 s0 = *reinterpret_cast<const float4*>(xn);
    float4 s1 = *reinterpret_cast<const float4*>(xn + 4);
    const int* nb = &sN[ln * 16];
#pragma unroll
    for (int k = 0; k < KNN; ++k) {
      const float* row = Xb + (size_t)nb[k] * 64 + d8;
      const float4 v0 = *reinterpret_cast<const float4*>(row);
      const float4 v1 = *reinterpret_cast<const float4*>(row + 4);
      s0.x += v0.x; s0.y += v0.y; s0.z += v0.z; s0.w += v0.w;
      s1.x += v1.x; s1.y += v1.y; s1.z += v1.z; s1.w += v1.w;
    }
    const float sc = 1.0f / 17.0f;
    sA[ln][d8 + 0] = s0.x * sc; sA[ln][d8 + 1] = s0.y * sc;
    sA[ln][d8 + 2] = s0.z * sc; sA[ln][d8 + 3] = s0.w * sc;
    sA[ln][d8 + 4] = s1.x * sc; sA[ln][d8 + 5] = s1.y * sc;
    sA[ln][d8 + 6] = s1.z * sc; sA[ln][d8 + 7] = s1.w * sc;
  }
  __syncthreads();

  const int ng = (t >> 5) * 4;   // first of 4 nodes
  const int o4 = (t & 31) * 4;   // 4 outputs

  // Phase B: x2 = relu(sA @ W2 + b2) -> sB  (K=64)
  {
    const float4 bv = *reinterpret_cast<const float4*>(b2 + o4);
    float4 acc0 = bv, acc1 = bv, acc2 = bv, acc3 = bv;
#pragma unroll 4
    for (int c = 0; c < 64; ++c) {
      const float4 w = *reinterpret_cast<const float4*>(W2 + (size_t)c * 128 + o4);
      const float a0 = sA[ng + 0][c];
      const float a1 = sA[ng + 1][c];
      const float a2 = sA[ng + 2][c];
      const float a3 = sA[ng + 3][c];
      acc0.x += a0 * w.x; acc0.y += a0 * w.y; acc0.z += a0 * w.z; acc0.w += a0 * w.w;
      acc1.x += a1 * w.x; acc1.y += a1 * w.y; acc1.z += a1 * w.z; acc1.w += a1 * w.w;
      acc2.x += a2 * w.x; acc2.y += a2 * w.y; acc2.z += a2 * w.z; acc2.w += a2 * w.w;
      acc3.x += a3 * w.x; acc3.y += a3 * w.y; acc3.z += a3 * w.z; acc3.w += a3 * w.w;
    }
    sB[ng + 0][o4 + 0] = fmaxf(acc0.x, 0.f); sB[ng + 0][o4 + 1] = fmaxf(acc0.y, 0.f);
    sB[ng + 0][o4 + 2] = fmaxf(acc0.z, 0.f); sB[ng + 0][o4 + 3] = fmaxf(acc0.w, 0.f);
    sB[ng + 1][o4 + 0] = fmaxf(acc1.x, 0.f); sB[ng + 1][o4 + 1] = fmaxf(acc1.y, 0.f);
    sB[ng + 1][o4 + 2] = fmaxf(acc1.z, 0.f); sB[ng + 1][o4 + 3] = fmaxf(acc1.w, 0.f);
    sB[ng + 2][o4 + 0] = fmaxf(acc2.x, 0.f); sB[ng + 2][o4 + 1] = fmaxf(acc2.y, 0.f);
    sB[ng + 2][o4 + 2] = fmaxf(acc2.z, 0.f); sB[ng + 2][o4 + 3] = fmaxf(acc2.w, 0.f);
    sB[ng + 3][o4 + 0] = fmaxf(acc3.x, 0.f); sB[ng + 3][o4 + 1] = fmaxf(acc3.y, 0.f);
    sB[ng + 3][o4 + 2] = fmaxf(acc3.z, 0.f); sB[ng + 3][o4 + 3] = fmaxf(acc3.w, 0.f);
  }
  __syncthreads();

  // Phase C: out = sB @ Wf + bf  (K=128)
  {
    const float4 bv = *reinterpret_cast<const float4*>(bf + o4);
    float4 acc0 = bv, acc1 = bv, acc2 = bv, acc3 = bv;
#pragma unroll 4
    for (int c = 0; c < 128; ++c) {
      const float4 w = *reinterpret_cast<const float4*>(Wf + (size_t)c * 128 + o4);
      const float a0 = sB[ng + 0][c];
      const float a1 = sB[ng + 1][c];
      const float a2 = sB[ng + 2][c];
      const float a3 = sB[ng + 3][c];
      acc0.x += a0 * w.x; acc0.y += a0 * w.y; acc0.z += a0 * w.z; acc0.w += a0 * w.w;
      acc1.x += a1 * w.x; acc1.y += a1 * w.y; acc1.z += a1 * w.z; acc1.w += a1 * w.w;
      acc2.x += a2 * w.x; acc2.y += a2 * w.y; acc2.z += a2 * w.z; acc2.w += a2 * w.w;
      acc3.x += a3 * w.x; acc3.y += a3 * w.y; acc3.z += a3 * w.z; acc3.w += a3 * w.w;
    }
    float* o0 = out + (size_t)(nodeBase + ng) * 128 + o4;
    *reinterpret_cast<float4*>(o0)       = acc0;
    *reinterpret_cast<float4*>(o0 + 128) = acc1;
    *reinterpret_cast<float4*>(o0 + 256) = acc2;
    *reinterpret_cast<float4*>(o0 + 384) = acc3;
  }
}

// ---------------------------------------------------------------------------
extern "C" void kernel_launch(void* const* d_in, const int* in_sizes, int n_in,
                              void* d_out, int out_size, void* d_ws, size_t ws_size,
                              hipStream_t stream) {
  const float* coords = (const float*)d_in[0];
  const float* W1 = (const float*)d_in[1];
  const float* b1 = (const float*)d_in[2];
  const float* W2 = (const float*)d_in[3];
  const float* b2 = (const float*)d_in[4];
  const float* Wf = (const float*)d_in[5];
  const float* bf = (const float*)d_in[6];
  float* out = (float*)d_out;

  char* ws = (char*)d_ws;
  int*   nbr = (int*)ws;                              // 1 MB
  float* x1  = (float*)(ws + (size_t)(1u << 20) * 1); // 4 MB

  // kNN + layer 1: one wave per node, 8 waves/block
  knn_l1_kernel<<<BATCH * (NN / 8), 512, 0, stream>>>(coords, W1, b1, nbr, x1);

  // layer 2 (aggregate + 64->128 + relu) fused with final 128->128 linear
  layers_kernel<<<(BATCH * NN) / 32, 256, 0, stream>>>(x1, nbr, W2, b2, Wf, bf, out);
}

// Round 11
// 112.390 us; speedup vs baseline: 1.1340x; 1.0059x over previous
//
#include <hip/hip_runtime.h>

#define NN    2048   // nodes per sample
#define KNN   16     // neighbors
#define BATCH 8

__device__ __forceinline__ unsigned umin_u(unsigned a, unsigned b) { return a < b ? a : b; }

// ---------------------------------------------------------------------------
// cross-lane helpers
// ---------------------------------------------------------------------------
__device__ __forceinline__ unsigned long long bcast64(unsigned long long v, int l) {
  unsigned lo = __builtin_amdgcn_readlane((unsigned)(v & 0xffffffffu), l);
  unsigned hi = __builtin_amdgcn_readlane((unsigned)(v >> 32), l);
  return ((unsigned long long)hi << 32) | lo;
}

// per-16-lane-row shift up by 1 (lane l <- lane l-1), lane 0 of each row -> 0.
__device__ __forceinline__ unsigned long long dpp_shr1_zero(unsigned long long v) {
  int lo = __builtin_amdgcn_update_dpp(0, (int)(unsigned)(v & 0xffffffffu), 0x111, 0xf, 0xf, true);
  int hi = __builtin_amdgcn_update_dpp(0, (int)(unsigned)(v >> 32),        0x111, 0xf, 0xf, true);
  return ((unsigned long long)(unsigned)hi << 32) | (unsigned)lo;
}

// ---------------------------------------------------------------------------
// Kernel 1: exact kNN (K=16), one WAVE per node, 8 waves/block, fused GCN L1.
// sP holds (-2x,-2y,-2z,|p|^2); d2' = (sqi+sqj+1) - 2*dot computed as
// add + 3 fma. The +1 offset keeps d2' > 0, so its raw float bits ARE the
// monotonic key (no sign-fold, 5 VALU/candidate). Keys cached in registers.
// tau = exact 17th-smallest of the 64 lane-minima (rank 17 absorbs self:
// the 17 smallest lane-minima are distinct-lane candidates, at most one is
// self => >=16 non-self keys <= tau). Selection ballots against constant
// tau; each survivor is inserted branchlessly into the lane-distributed
// sorted top-16 (pk = row-shift(lk); lk = min(lk, max(pk, c))); the 64-bit
// key is packed lazily (readlane + SALU) only when inserting.
// Unseeded rerun kept as insurance; gathered indices clamped.
// ---------------------------------------------------------------------------
__global__ __launch_bounds__(512) void knn_l1_kernel(const float* __restrict__ coords,
                                                     const float* __restrict__ W1,
                                                     const float* __restrict__ b1,
                                                     int* __restrict__ nbr,
                                                     float* __restrict__ x1) {
  __shared__ float4 sP[NN];  // -2x,-2y,-2z,|p|^2  (32 KB)

  const int b        = blockIdx.x >> 8;          // 256 blocks per sample
  const int nodeBase = (blockIdx.x & 255) << 3;  // 8 nodes per block
  const int lane     = (int)threadIdx.x & 63;
  const int wid      = (int)threadIdx.x >> 6;

  const float* cb = coords + (size_t)b * NN * 6;
  for (int p = threadIdx.x; p < NN; p += 512) {
    const float2 v01 = *reinterpret_cast<const float2*>(cb + p * 6);
    const float2 v23 = *reinterpret_cast<const float2*>(cb + p * 6 + 2);
    const float x = v01.x, y = v01.y, z = v23.x;
    float4 v; v.x = -2.0f * x; v.y = -2.0f * y; v.z = -2.0f * z;
    v.w = x * x + y * y + z * z;
    sP[p] = v;
  }
  __syncthreads();

  const int i = nodeBase + wid;
  const float4 pi = sP[i];
  const float xi = pi.x * -0.5f, yi = pi.y * -0.5f, zi = pi.z * -0.5f;
  const float base = pi.w + 1.0f;   // +1 keeps d2' strictly positive

  // ---- single distance pass: cache 32 positive-key bits, track lane min ----
  unsigned key[32];          // static indices only -> stays in VGPRs
  unsigned lmin = 0xFFFFFFFFu;
#pragma unroll
  for (int it = 0; it < 32; ++it) {
    const float4 pj = sP[(it << 6) + lane];
    const float d2 = fmaf(pj.x, xi, fmaf(pj.y, yi, fmaf(pj.z, zi, pj.w + base)));
    const unsigned k32 = __float_as_uint(d2);   // positive => bits monotonic
    key[it] = k32;
    lmin = umin_u(lmin, k32);
  }

  // exact 17th-smallest of the 64 lane-minima (self occupies one rank at most)
  unsigned tau = 0u;
  for (int bit = 31; bit >= 0; --bit) {
    const unsigned t_try = tau + ((1u << bit) - 1u);
    const unsigned long long m = __ballot(lmin <= t_try);
    if (__popcll(m) < 17) tau += (1u << bit);
  }

  // ---- selection over cached keys: constant-tau ballot, branchless insert --
  unsigned long long lk = ~0ull;   // lane k (k<16): k-th smallest so far
  unsigned thr = tau;

  for (int attempt = 0; attempt < 2; ++attempt) {
#pragma unroll
    for (int it = 0; it < 32; ++it) {
      const int j = (it << 6) + lane;
      unsigned long long mask = __ballot(key[it] <= thr && j != i);
      while (mask) {
        const int src = __ffsll((unsigned long long)mask) - 1;
        mask &= mask - 1;
        const unsigned ckey = __builtin_amdgcn_readlane(key[it], src);  // lazy pack
        const unsigned long long c =
            ((unsigned long long)ckey << 32) | (unsigned)((it << 6) + src);
        const unsigned long long pk = dpp_shr1_zero(lk);      // row shift-up
        const unsigned long long mx = (pk > c) ? pk : c;
        lk = (lk < mx) ? lk : mx;                             // sorted insert
      }
    }
    if (bcast64(lk, 15) != ~0ull) break;  // >=16 entries (theorem; always true)
    lk = ~0ull; thr = 0xFFFFFFFFu;        // insurance: exact unseeded rerun
  }

  // clamped index: a sentinel can never reach memory
  const int nj = (int)umin_u((unsigned)(lk & 0xffffffffu), NN - 1u);
  if (lane < KNN) {
    nbr[((size_t)b * NN + i) * KNN + lane] = nj;
  }

  // ---- fused GCN layer 1: x1[i] = relu( ((sum_nbr c + c_i)/17) @ W1 + b1 ) ----
  float r[6];
#pragma unroll
  for (int c = 0; c < 6; ++c) r[c] = 0.f;
  if (lane < KNN) {
    const float* row = cb + (size_t)nj * 6;
    const float2 a = *reinterpret_cast<const float2*>(row);
    const float2 m = *reinterpret_cast<const float2*>(row + 2);
    const float2 q = *reinterpret_cast<const float2*>(row + 4);
    r[0] = a.x; r[1] = a.y; r[2] = m.x; r[3] = m.y; r[4] = q.x; r[5] = q.y;
  }
#pragma unroll
  for (int m = 1; m <= 8; m <<= 1) {
#pragma unroll
    for (int c = 0; c < 6; ++c) r[c] += __shfl_xor(r[c], m);
  }
  const float* self = cb + (size_t)i * 6;
  float agg[6];
#pragma unroll
  for (int c = 0; c < 6; ++c) {
    const float nbs = __uint_as_float(__builtin_amdgcn_readfirstlane(__float_as_uint(r[c])));
    agg[c] = (nbs + self[c]) * (1.0f / 17.0f);
  }
  float acc = b1[lane];
#pragma unroll
  for (int c = 0; c < 6; ++c) acc = fmaf(agg[c], W1[c * 64 + lane], acc);
  x1[((size_t)b * NN + i) * 64 + lane] = fmaxf(acc, 0.f);
}

// ---------------------------------------------------------------------------
// Kernel 2: fused GCN layer 2 + final Linear, register-tiled (unchanged:
// 32 nodes / 256 threads / 512 blocks, XCD-swizzled).
// ---------------------------------------------------------------------------
__global__ __launch_bounds__(256) void layers_kernel(const float* __restrict__ x1,
                                                     const int* __restrict__ nbr,
                                                     const float* __restrict__ W2,
                                                     const float* __restrict__ b2,
                                                     const float* __restrict__ Wf,
                                                     const float* __restrict__ bf,
                                                     float* __restrict__ out) {
  __shared__ float sA[32][68];    // aggregated x1 (pad 4)
  __shared__ float sB[32][132];   // x2 tile      (pad 4)
  __shared__ int   sN[512];

  const int t   = (int)threadIdx.x;
  const int bid = (int)blockIdx.x;
  // XCD swizzle: XCD k (= bid%8) exclusively processes sample k's 64 tiles
  const int swz = (bid & 7) * 64 + (bid >> 3);
  const int nodeBase = swz * 32;
  const int bs       = nodeBase >> 11;          // sample index (32 | 2048)

  // neighbor lists for 32 nodes (clamped: sentinel can never reach memory)
  sN[t]       = (int)umin_u((unsigned)nbr[(size_t)nodeBase * KNN + t],       NN - 1u);
  sN[t + 256] = (int)umin_u((unsigned)nbr[(size_t)nodeBase * KNN + t + 256], NN - 1u);
  __syncthreads();

  // Phase A: gather-aggregate x1 (thread = node t>>3, dims (t&7)*8 .. +7)
  {
    const int ln = t >> 3;
    const int d8 = (t & 7) * 8;
    const int n  = nodeBase + ln;
    const float* Xb = x1 + (((size_t)bs) << 11) * 64;
    const float* xn = x1 + (size_t)n * 64 + d8;
    float4 s0 = *reinterpret_cast<const float4*>(xn);
    float4 s1 = *reinterpret_cast<const float4*>(xn + 4);
    const int* nb = &sN[ln * 16];
#pragma unroll
    for (int k = 0; k < KNN; ++k) {
      const float* row = Xb + (size_t)nb[k] * 64 + d8;
      const float4 v0 = *reinterpret_cast<const float4*>(row);
      const float4 v1 = *reinterpret_cast<const float4*>(row + 4);
      s0.x += v0.x; s0.y += v0.y; s0.z += v0.z; s0.w += v0.w;
      s1.x += v1.x; s1.y += v1.y; s1.z += v1.z; s1.w += v1.w;
    }
    const float sc = 1.0f / 17.0f;
    sA[ln][d8 + 0] = s0.x * sc; sA[ln][d8 + 1] = s0.y * sc;
    sA[ln][d8 + 2] = s0.z * sc; sA[ln][d8 + 3] = s0.w * sc;
    sA[ln][d8 + 4] = s1.x * sc; sA[ln][d8 + 5] = s1.y * sc;
    sA[ln][d8 + 6] = s1.z * sc; sA[ln][d8 + 7] = s1.w * sc;
  }
  __syncthreads();

  const int ng = (t >> 5) * 4;   // first of 4 nodes
  const int o4 = (t & 31) * 4;   // 4 outputs

  // Phase B: x2 = relu(sA @ W2 + b2) -> sB  (K=64)
  {
    const float4 bv = *reinterpret_cast<const float4*>(b2 + o4);
    float4 acc0 = bv, acc1 = bv, acc2 = bv, acc3 = bv;
#pragma unroll 4
    for (int c = 0; c < 64; ++c) {
      const float4 w = *reinterpret_cast<const float4*>(W2 + (size_t)c * 128 + o4);
      const float a0 = sA[ng + 0][c];
      const float a1 = sA[ng + 1][c];
      const float a2 = sA[ng + 2][c];
      const float a3 = sA[ng + 3][c];
      acc0.x += a0 * w.x; acc0.y += a0 * w.y; acc0.z += a0 * w.z; acc0.w += a0 * w.w;
      acc1.x += a1 * w.x; acc1.y += a1 * w.y; acc1.z += a1 * w.z; acc1.w += a1 * w.w;
      acc2.x += a2 * w.x; acc2.y += a2 * w.y; acc2.z += a2 * w.z; acc2.w += a2 * w.w;
      acc3.x += a3 * w.x; acc3.y += a3 * w.y; acc3.z += a3 * w.z; acc3.w += a3 * w.w;
    }
    sB[ng + 0][o4 + 0] = fmaxf(acc0.x, 0.f); sB[ng + 0][o4 + 1] = fmaxf(acc0.y, 0.f);
    sB[ng + 0][o4 + 2] = fmaxf(acc0.z, 0.f); sB[ng + 0][o4 + 3] = fmaxf(acc0.w, 0.f);
    sB[ng + 1][o4 + 0] = fmaxf(acc1.x, 0.f); sB[ng + 1][o4 + 1] = fmaxf(acc1.y, 0.f);
    sB[ng + 1][o4 + 2] = fmaxf(acc1.z, 0.f); sB[ng + 1][o4 + 3] = fmaxf(acc1.w, 0.f);
    sB[ng + 2][o4 + 0] = fmaxf(acc2.x, 0.f); sB[ng + 2][o4 + 1] = fmaxf(acc2.y, 0.f);
    sB[ng + 2][o4 + 2] = fmaxf(acc2.z, 0.f); sB[ng + 2][o4 + 3] = fmaxf(acc2.w, 0.f);
    sB[ng + 3][o4 + 0] = fmaxf(acc3.x, 0.f); sB[ng + 3][o4 + 1] = fmaxf(acc3.y, 0.f);
    sB[ng + 3][o4 + 2] = fmaxf(acc3.z, 0.f); sB[ng + 3][o4 + 3] = fmaxf(acc3.w, 0.f);
  }
  __syncthreads();

  // Phase C: out = sB @ Wf + bf  (K=128)
  {
    const float4 bv = *reinterpret_cast<const float4*>(bf + o4);
    float4 acc0 = bv, acc1 = bv, acc2 = bv, acc3 = bv;
#pragma unroll 4
    for (int c = 0; c < 128; ++c) {
      const float4 w = *reinterpret_cast<const float4*>(Wf + (size_t)c * 128 + o4);
      const float a0 = sB[ng + 0][c];
      const float a1 = sB[ng + 1][c];
      const float a2 = sB[ng + 2][c];
      const float a3 = sB[ng + 3][c];
      acc0.x += a0 * w.x; acc0.y += a0 * w.y; acc0.z += a0 * w.z; acc0.w += a0 * w.w;
      acc1.x += a1 * w.x; acc1.y += a1 * w.y; acc1.z += a1 * w.z; acc1.w += a1 * w.w;
      acc2.x += a2 * w.x; acc2.y += a2 * w.y; acc2.z += a2 * w.z; acc2.w += a2 * w.w;
      acc3.x += a3 * w.x; acc3.y += a3 * w.y; acc3.z += a3 * w.z; acc3.w += a3 * w.w;
    }
    float* o0 = out + (size_t)(nodeBase + ng) * 128 + o4;
    *reinterpret_cast<float4*>(o0)       = acc0;
    *reinterpret_cast<float4*>(o0 + 128) = acc1;
    *reinterpret_cast<float4*>(o0 + 256) = acc2;
    *reinterpret_cast<float4*>(o0 + 384) = acc3;
  }
}

// ---------------------------------------------------------------------------
extern "C" void kernel_launch(void* const* d_in, const int* in_sizes, int n_in,
                              void* d_out, int out_size, void* d_ws, size_t ws_size,
                              hipStream_t stream) {
  const float* coords = (const float*)d_in[0];
  const float* W1 = (const float*)d_in[1];
  const float* b1 = (const float*)d_in[2];
  const float* W2 = (const float*)d_in[3];
  const float* b2 = (const float*)d_in[4];
  const float* Wf = (const float*)d_in[5];
  const float* bf = (const float*)d_in[6];
  float* out = (float*)d_out;

  char* ws = (char*)d_ws;
  int*   nbr = (int*)ws;                              // 1 MB
  float* x1  = (float*)(ws + (size_t)(1u << 20) * 1); // 4 MB

  // kNN + layer 1: one wave per node, 8 waves/block
  knn_l1_kernel<<<BATCH * (NN / 8), 512, 0, stream>>>(coords, W1, b1, nbr, x1);

  // layer 2 (aggregate + 64->128 + relu) fused with final 128->128 linear
  layers_kernel<<<(BATCH * NN) / 32, 256, 0, stream>>>(x1, nbr, W2, b2, Wf, bf, out);
}